// Round 7
// baseline (316.570 us; speedup 1.0000x reference)
//
#include <hip/hip_runtime.h>

// TemplatePointwiseAttention, MI355X/gfx950.
// Folded-weight formulation: G = Z @ Abar (MFMA), 4-way softmax, OUT = S @ Mbar.
// R7: de-lockstep at constant tile size. PB=32, 8 waves, 18 tiles, 1 block/CU.
// Wave = (pair-half mt, head hh). ONE barrier per tile:
//   [BAR] G2(k-1) | G1(k)->sGw (wave-local) | DMA(k+2) | zb(k+1) | lgkm0 |
//   attn(k): sGw+sT -> sS[k&1] | [BAR]
// G1->attn bounce is per-wave LDS scratch (no barrier); only S->G2 syncs.
// DMA ring-3 dist-2; DMA(k+2) issued BEFORE zb(k+1) so every wave's G1(k+1)
// zb-wait retires it one full barrier before any attn(k+2) read (R4/R6-proven
// in-order vmcnt chain). Prologue: vmcnt(8)+barrier for tiles 0,1.
// exp2 path: 0.125*log2(e) folded into Abar at prep.
// LDS: sT 3x32K + sS 2x16K + sGw 16K = 144 KB (1 block/CU, 8 waves).

#define R_    384
#define P_    (R_ * R_)      // 147456 residue pairs
#define PB    32             // pairs per tile
#define NPB   256            // persistent blocks = CUs
#define NT_   18             // tiles per block

typedef __attribute__((ext_vector_type(8))) short  short8;   // 8 x bf16 MFMA frag
typedef __attribute__((ext_vector_type(4))) float  f32x4;    // MFMA accumulator

union S8U { short8 s8; unsigned u[4]; };

__device__ __forceinline__ unsigned short f2bf(float f) {
  unsigned u = __float_as_uint(f);
  unsigned r = ((u >> 16) & 1u) + 0x7FFFu;   // RNE
  return (unsigned short)((u + r) >> 16);
}
__device__ __forceinline__ float bf2f(unsigned short s) {
  return __uint_as_float(((unsigned)s) << 16);
}
__device__ __forceinline__ unsigned cvtpk(float lo, float hi) {
  unsigned d;
  asm("v_cvt_pk_bf16_f32 %0, %1, %2" : "=v"(d) : "v"(lo), "v"(hi));
  return d;
}
#define SB() __builtin_amdgcn_sched_barrier(0)
// Raw barrier: LDS drain only — in-flight VMEM (DMA/z prefetch) crosses it.
#define BAR() do { \
    asm volatile("s_waitcnt lgkmcnt(0)\ns_barrier" ::: "memory"); \
    SB(); \
  } while (0)

__device__ __forceinline__ void dma16(const float* g, void* lds) {
  // 16B per lane; LDS dest = wave-uniform base + lane*16 (HW adds lane part).
  __builtin_amdgcn_global_load_lds((const __attribute__((address_space(1))) unsigned*)g,
                                   (__attribute__((address_space(3))) unsigned*)lds,
                                   16, 0, 0);
}

// ---- K0: fold weights into AbarT[n=256][i=128], MbarT[o=128][k=256] (bf16) ----
// Abar carries 1/sqrt(64) AND log2(e): logits land in exp2 domain.
__global__ void prep_kernel(const float* __restrict__ Wq, const float* __restrict__ Wk,
                            const float* __restrict__ Wv, const float* __restrict__ Wo,
                            unsigned short* __restrict__ AbarT,
                            unsigned short* __restrict__ MbarT) {
  int tid = blockIdx.x * blockDim.x + threadIdx.x;   // 65536 threads
  if (tid < 256 * 128) {
    int n = tid >> 7, i = tid & 127;
    int h = n >> 6, j = n & 63;
    const float* wq = Wq + i * 256 + h * 64;
    const float* wk = Wk + j * 256 + h * 64;
    float acc = 0.f;
#pragma unroll 8
    for (int c = 0; c < 64; ++c) acc += wq[c] * wk[c];
    AbarT[n * 128 + i] = f2bf(acc * (0.125f * 1.44269504088896f));
  } else {
    int t2 = tid - 256 * 128;
    int o = t2 >> 8, k = t2 & 255;
    int h = k >> 6, j = k & 63;
    const float* wv = Wv + j * 256 + h * 64;
    const float* wo = Wo + (h * 64) * 128 + o;
    float acc = 0.f;
#pragma unroll 8
    for (int c = 0; c < 64; ++c) acc += wv[c] * wo[c * 128];
    MbarT[o * 256 + k] = f2bf(acc);
  }
}

// ---- persistent fused kernel ----
__global__ __launch_bounds__(512, 2) void attn_kernel(
    const float* __restrict__ z2d, const float* __restrict__ t2d,
    const unsigned short* __restrict__ AbarT, const unsigned short* __restrict__ MbarT,
    const float* __restrict__ bo, float* __restrict__ out) {
  extern __shared__ char smem[];
  float*          sTf = (float*)smem;                      // 3 x [4t][32p][64c] fp32 (96K)
  unsigned short* sS  = (unsigned short*)(smem + 98304);   // 2 x [32][256] bf16 swz (32K)
  unsigned short* sGw = (unsigned short*)(smem + 131072);  // 8 x [16][64] bf16 swz (16K)

  const int tid  = threadIdx.x;
  const int wv_  = tid >> 6;   // wave id
  const int lane = tid & 63;
  const int l = lane & 15;     // MFMA A row / B col / D col
  const int q = lane >> 4;     // MFMA quad
  const int mt = wv_ & 1;      // pair-half (16 rows)
  const int hh = wv_ >> 1;     // head

  const int pr = mt * 16 + l;  // this lane's pair row (G1 A-row, attn pair)

  // ---- weights -> regs (wave-sliced) ----
  short8 ab[4][4];             // Abar head-slice: cols (hh*64 + i*16 + l)
#pragma unroll
  for (int kk = 0; kk < 4; ++kk)
#pragma unroll
    for (int i = 0; i < 4; ++i)
      ab[kk][i] = *(const short8*)(AbarT + (hh * 64 + i * 16 + l) * 128 + kk * 32 + q * 8);
  short8 mb[8];                // Mbar o-slice: o = wv_*16 + l
#pragma unroll
  for (int kk = 0; kk < 8; ++kk)
    mb[kk] = *(const short8*)(MbarT + (size_t)(wv_ * 16 + l) * 256 + kk * 32 + q * 8);
  const float boR = bo[wv_ * 16 + l];
  SB();

  // ---- DMA geometry: wave covers rows R = wv_*16 + m*4 + q of [t*32+p] ----
  size_t soff[4];              // (t*P_ + p)*64 + swizzled chunk, float units
#pragma unroll
  for (int m = 0; m < 4; ++m) {
    const int R = wv_ * 16 + m * 4 + q;
    soff[m] = ((size_t)(R >> 5) * P_ + (R & 31)) * 64 + ((l ^ (R & 7)) << 2);
  }
  // ---- attn T-read offsets (float units within a slot; + t*2048) ----
  int aoT[4];
#pragma unroll
  for (int j = 0; j < 4; ++j)
    aoT[j] = pr * 64 + (((4 * q + j) ^ (pr & 7)) << 2);

  // ---- prologue: DMA(0)->slot0, DMA(1)->slot1, zb(0); vmcnt(8)+barrier ----
  const size_t P00 = (size_t)blockIdx.x * PB;
#pragma unroll
  for (int s = 0; s < 2; ++s) {
    const size_t P0s64 = (P00 + (size_t)s * NPB * PB) * 64;
    char* dst = (char*)sTf + s * 32768 + wv_ * 4096;
#pragma unroll
    for (int m = 0; m < 4; ++m)
      dma16(t2d + P0s64 + soff[m], dst + m * 1024);
  }
  SB();
  float4 zb[8];
  {
    const float* zr = z2d + (P00 + pr) * 128;
#pragma unroll
    for (int kk = 0; kk < 4; ++kk) {
      zb[2 * kk]     = *(const float4*)(zr + kk * 32 + q * 8);
      zb[2 * kk + 1] = *(const float4*)(zr + kk * 32 + q * 8 + 4);
    }
  }
  SB();
  asm volatile("s_waitcnt vmcnt(8)\ns_barrier" ::: "memory");  // slots 0,1 landed
  SB();

#pragma unroll 1
  for (int k = 0; k < NT_; ++k) {
    const int slT = k % 3;
    const int slG = k & 1;
    const size_t P0 = P00 + (size_t)k * NPB * PB;

    // (1) GEMM2 tile k-1: S(sS[(k-1)&1]) @ Mbar(regs) -> out
    if (k > 0) {
      const unsigned short* sSp = sS + (slG ^ 1) * 8192;
      f32x4 a20 = f32x4{0.f, 0.f, 0.f, 0.f};
      f32x4 a21 = f32x4{0.f, 0.f, 0.f, 0.f};
#pragma unroll
      for (int kk = 0; kk < 8; ++kk) {
        const int r0 = l, r1 = 16 + l;
        short8 af0 = *(const short8*)(sSp + r0 * 256 + (((kk * 4 + q) ^ r0) << 3));
        short8 af1 = *(const short8*)(sSp + r1 * 256 + (((kk * 4 + q) ^ (r1 & 31)) << 3));
        a20 = __builtin_amdgcn_mfma_f32_16x16x32_bf16(af0, mb[kk], a20, 0, 0, 0);
        a21 = __builtin_amdgcn_mfma_f32_16x16x32_bf16(af1, mb[kk], a21, 0, 0, 0);
      }
      const size_t P0p = P0 - (size_t)NPB * PB;
#pragma unroll
      for (int r = 0; r < 4; ++r) {
        out[(P0p + q * 4 + r) * 128 + wv_ * 16 + l]      = a20[r] + boR;
        out[(P0p + 16 + q * 4 + r) * 128 + wv_ * 16 + l] = a21[r] + boR;
      }
    }
    SB();
    // (2) GEMM1 tile k: zb-wait retires DMA(k+1) (issued last iter, pre-zb(k)).
    //     G (head-slice) -> per-wave scratch sGw (wave-local, no barrier).
    {
      f32x4 a1[4];
#pragma unroll
      for (int i = 0; i < 4; ++i) a1[i] = f32x4{0.f, 0.f, 0.f, 0.f};
#pragma unroll
      for (int kk = 0; kk < 4; ++kk) {
        S8U af;
        af.u[0] = cvtpk(zb[2 * kk].x,     zb[2 * kk].y);
        af.u[1] = cvtpk(zb[2 * kk].z,     zb[2 * kk].w);
        af.u[2] = cvtpk(zb[2 * kk + 1].x, zb[2 * kk + 1].y);
        af.u[3] = cvtpk(zb[2 * kk + 1].z, zb[2 * kk + 1].w);
#pragma unroll
        for (int i = 0; i < 4; ++i)
          a1[i] = __builtin_amdgcn_mfma_f32_16x16x32_bf16(af.s8, ab[kk][i], a1[i], 0, 0, 0);
      }
      unsigned short* gw = sGw + wv_ * 1024;
#pragma unroll
      for (int i = 0; i < 4; ++i) {
#pragma unroll
        for (int r = 0; r < 4; ++r) {
          const int row = q * 4 + r;                       // D[m=q*4+r][n=l]
          gw[row * 64 + (((2 * i + (l >> 3)) ^ (row & 7)) << 3) + (l & 7)]
              = f2bf(a1[i][r]);
        }
      }
    }
    SB();
    // (3) DMA(k+2) -> slot (k+2)%3 (BEFORE zb(k+1): older -> retired by every
    //     wave's G1(k+1) zb-wait, one barrier before attn(k+2) reads it)
    if (k + 2 < NT_) {
      const size_t P0264 = (P0 + 2 * (size_t)NPB * PB) * 64;
      char* dst = (char*)sTf + ((k + 2) % 3) * 32768 + wv_ * 4096;
#pragma unroll
      for (int m = 0; m < 4; ++m)
        dma16(t2d + P0264 + soff[m], dst + m * 1024);
    }
    SB();
    // (4) zb(k+1)
    if (k + 1 < NT_) {
      const float* zr = z2d + (P0 + (size_t)NPB * PB + pr) * 128;
#pragma unroll
      for (int kk = 0; kk < 4; ++kk) {
        zb[2 * kk]     = *(const float4*)(zr + kk * 32 + q * 8);
        zb[2 * kk + 1] = *(const float4*)(zr + kk * 32 + q * 8 + 4);
      }
    }
    SB();
    // (5) wave-local G visibility
    asm volatile("s_waitcnt lgkmcnt(0)" ::: "memory");
    SB();
    // (6) attention tile k: pair pr, head hh, quarter q (all wave-private)
    {
      const float* Kt = sTf + slT * 8192;
      const unsigned short* gw = sGw + wv_ * 1024;
      short8 g0 = *(const short8*)(gw + l * 64 + (((2 * q) ^ (l & 7)) << 3));
      short8 g1 = *(const short8*)(gw + l * 64 + (((2 * q + 1) ^ (l & 7)) << 3));
      float gk[16];
#pragma unroll
      for (int e = 0; e < 8; ++e) {
        gk[e]     = bf2f((unsigned short)g0[e]);
        gk[8 + e] = bf2f((unsigned short)g1[e]);
      }
      float lg0 = 0.f, lg1 = 0.f, lg2 = 0.f, lg3 = 0.f;
#pragma unroll
      for (int j = 0; j < 4; ++j) {
        float4 k0 = *(const float4*)(Kt +        aoT[j]);
        float4 k1 = *(const float4*)(Kt + 2048 + aoT[j]);
        float4 k2 = *(const float4*)(Kt + 4096 + aoT[j]);
        float4 k3 = *(const float4*)(Kt + 6144 + aoT[j]);
        const float ga = gk[4 * j], gb = gk[4 * j + 1];
        const float gc = gk[4 * j + 2], gd = gk[4 * j + 3];
        lg0 += ga * k0.x + gb * k0.y + gc * k0.z + gd * k0.w;
        lg1 += ga * k1.x + gb * k1.y + gc * k1.z + gd * k1.w;
        lg2 += ga * k2.x + gb * k2.y + gc * k2.z + gd * k2.w;
        lg3 += ga * k3.x + gb * k3.y + gc * k3.z + gd * k3.w;
      }
      // combine quarters: lanes l, l+16, l+32, l+48
      lg0 += __shfl_xor(lg0, 16); lg0 += __shfl_xor(lg0, 32);
      lg1 += __shfl_xor(lg1, 16); lg1 += __shfl_xor(lg1, 32);
      lg2 += __shfl_xor(lg2, 16); lg2 += __shfl_xor(lg2, 32);
      lg3 += __shfl_xor(lg3, 16); lg3 += __shfl_xor(lg3, 32);
      const float mx = fmaxf(fmaxf(lg0, lg1), fmaxf(lg2, lg3));
      float e0 = exp2f(lg0 - mx), e1 = exp2f(lg1 - mx);   // log2e folded in Abar
      float e2 = exp2f(lg2 - mx), e3 = exp2f(lg3 - mx);
      const float inv = 1.f / (e0 + e1 + e2 + e3);
      e0 *= inv; e1 *= inv; e2 *= inv; e3 *= inv;
      asm volatile("" ::: "memory");   // force K re-read (cap VGPR peak)
      unsigned short* sSc = sS + slG * 8192;
#pragma unroll
      for (int j = 0; j < 4; ++j) {
        float4 k0 = *(const float4*)(Kt +        aoT[j]);
        float4 k1 = *(const float4*)(Kt + 2048 + aoT[j]);
        float4 k2 = *(const float4*)(Kt + 4096 + aoT[j]);
        float4 k3 = *(const float4*)(Kt + 6144 + aoT[j]);
        float s0 = e0 * k0.x + e1 * k1.x + e2 * k2.x + e3 * k3.x;
        float s1 = e0 * k0.y + e1 * k1.y + e2 * k2.y + e3 * k3.y;
        float s2 = e0 * k0.z + e1 * k1.z + e2 * k2.z + e3 * k3.z;
        float s3 = e0 * k0.w + e1 * k1.w + e2 * k2.w + e3 * k3.w;
        const int c = hh * 64 + q * 16 + j * 4;
        uint2 w2; w2.x = cvtpk(s0, s1); w2.y = cvtpk(s2, s3);
        *(uint2*)(sSc + pr * 256 + ((((c >> 3) ^ (pr & 31)) << 3) | (c & 7))) = w2;
      }
    }
    BAR();
  }

  // ---- tail: GEMM2 for the last tile (slot (NT_-1)&1 = 1) ----
  {
    const unsigned short* sSp = sS + 8192;
    f32x4 a20 = f32x4{0.f, 0.f, 0.f, 0.f};
    f32x4 a21 = f32x4{0.f, 0.f, 0.f, 0.f};
#pragma unroll
    for (int kk = 0; kk < 8; ++kk) {
      const int r0 = l, r1 = 16 + l;
      short8 af0 = *(const short8*)(sSp + r0 * 256 + (((kk * 4 + q) ^ r0) << 3));
      short8 af1 = *(const short8*)(sSp + r1 * 256 + (((kk * 4 + q) ^ (r1 & 31)) << 3));
      a20 = __builtin_amdgcn_mfma_f32_16x16x32_bf16(af0, mb[kk], a20, 0, 0, 0);
      a21 = __builtin_amdgcn_mfma_f32_16x16x32_bf16(af1, mb[kk], a21, 0, 0, 0);
    }
    const size_t P0p = P00 + (size_t)(NT_ - 1) * NPB * PB;
#pragma unroll
    for (int r = 0; r < 4; ++r) {
      out[(P0p + q * 4 + r) * 128 + wv_ * 16 + l]      = a20[r] + boR;
      out[(P0p + 16 + q * 4 + r) * 128 + wv_ * 16 + l] = a21[r] + boR;
    }
  }
}

extern "C" void kernel_launch(void* const* d_in, const int* in_sizes, int n_in,
                              void* d_out, int out_size, void* d_ws, size_t ws_size,
                              hipStream_t stream) {
  const float* z2d = (const float*)d_in[0];
  const float* t2d = (const float*)d_in[1];
  const float* Wq  = (const float*)d_in[2];
  const float* Wk  = (const float*)d_in[3];
  const float* Wv  = (const float*)d_in[4];
  const float* Wo  = (const float*)d_in[5];
  const float* bo  = (const float*)d_in[6];

  unsigned short* AbarT = (unsigned short*)d_ws;           // 256*128 bf16 = 64 KB
  unsigned short* MbarT = AbarT + 256 * 128;               // 128*256 bf16 = 64 KB
  float* out = (float*)d_out;

  static bool attr_set = false;
  if (!attr_set) {
    (void)hipFuncSetAttribute((const void*)attn_kernel,
                              hipFuncAttributeMaxDynamicSharedMemorySize, 147456);
    attr_set = true;
  }

  hipLaunchKernelGGL(prep_kernel, dim3(256), dim3(256), 0, stream,
                     Wq, Wk, Wv, Wo, AbarT, MbarT);
  hipLaunchKernelGGL(attn_kernel, dim3(NPB), dim3(512), 147456, stream,
                     z2d, t2d, AbarT, MbarT, bo, out);
}

// Round 8
// 310.668 us; speedup vs baseline: 1.0190x; 1.0190x over previous
//
#include <hip/hip_runtime.h>

// TemplatePointwiseAttention, MI355X/gfx950.
// Folded-weight formulation: G = Z @ Abar (MFMA), 4-way softmax, OUT = S @ Mbar.
// R8 = R4 minus the t2d LDS path. Diagnosis: LDS pipe (no busy counter in our
// PMC set!) was ~60-70% occupied per tile — K staged via DMA then read TWICE
// (2KB/pair) dominated; t2d has zero cross-thread reuse so LDS staging was
// pure overhead (Common-mistake #7). Now: attention threads load K (4t x 16c
// = 16 float4) DIRECTLY global->regs, issued end of Y(k-1) (in flight across
// BAR+G2+G1), used for logits, HELD through softmax, reused from regs for the
// S-pass (second K read eliminated). 4-way duplicate loads across heads are
// same-wave same-address -> coalesced/L1-merged. All DMA machinery deleted.
// LDS: sAbar 64K + sG 2x16K = 96 KB (1 block/CU, 8 waves).

#define R_    384
#define P_    (R_ * R_)      // 147456 residue pairs
#define PB    32             // pairs per tile
#define NPB   256            // persistent blocks = CUs
#define NT_   18             // tiles per block

typedef __attribute__((ext_vector_type(8))) short  short8;   // 8 x bf16 MFMA frag
typedef __attribute__((ext_vector_type(4))) float  f32x4;    // MFMA accumulator

union S8U { short8 s8; unsigned u[4]; };

__device__ __forceinline__ unsigned short f2bf(float f) {
  unsigned u = __float_as_uint(f);
  unsigned r = ((u >> 16) & 1u) + 0x7FFFu;   // RNE
  return (unsigned short)((u + r) >> 16);
}
__device__ __forceinline__ float bf2f(unsigned short s) {
  return __uint_as_float(((unsigned)s) << 16);
}
__device__ __forceinline__ unsigned cvtpk(float lo, float hi) {
  unsigned d;
  asm("v_cvt_pk_bf16_f32 %0, %1, %2" : "=v"(d) : "v"(lo), "v"(hi));
  return d;
}
// bf16 LDS tiles [p][c] (p<32, c<256), pitch 256, XOR-swizzled in 16B blocks.
__device__ __forceinline__ int swz(int p, int c) {
  return p * 256 + ((((c >> 3) ^ (p & 31)) << 3) | (c & 7));
}
#define SB() __builtin_amdgcn_sched_barrier(0)
// Raw barrier: LDS drain only — in-flight VMEM (K/z prefetch) crosses it.
#define BAR() do { \
    asm volatile("s_waitcnt lgkmcnt(0)\ns_barrier" ::: "memory"); \
    SB(); \
  } while (0)

// ---- K0: fold weights into AbarT[n=256][i=128], MbarT[o=128][k=256] (bf16) ----
__global__ void prep_kernel(const float* __restrict__ Wq, const float* __restrict__ Wk,
                            const float* __restrict__ Wv, const float* __restrict__ Wo,
                            unsigned short* __restrict__ AbarT,
                            unsigned short* __restrict__ MbarT) {
  int tid = blockIdx.x * blockDim.x + threadIdx.x;   // 65536 threads
  if (tid < 256 * 128) {
    int n = tid >> 7, i = tid & 127;
    int h = n >> 6, j = n & 63;
    const float* wq = Wq + i * 256 + h * 64;
    const float* wk = Wk + j * 256 + h * 64;
    float acc = 0.f;
#pragma unroll 8
    for (int c = 0; c < 64; ++c) acc += wq[c] * wk[c];
    AbarT[n * 128 + i] = f2bf(acc * 0.125f);         // 1/sqrt(64) folded in
  } else {
    int t2 = tid - 256 * 128;
    int o = t2 >> 8, k = t2 & 255;
    int h = k >> 6, j = k & 63;
    const float* wv = Wv + j * 256 + h * 64;
    const float* wo = Wo + (h * 64) * 128 + o;
    float acc = 0.f;
#pragma unroll 8
    for (int c = 0; c < 64; ++c) acc += wv[c] * wo[c * 128];
    MbarT[o * 256 + k] = f2bf(acc);
  }
}

// ---- persistent fused kernel ----
__global__ __launch_bounds__(512, 2) void attn_kernel(
    const float* __restrict__ z2d, const float* __restrict__ t2d,
    const unsigned short* __restrict__ AbarT, const unsigned short* __restrict__ MbarT,
    const float* __restrict__ bo, float* __restrict__ out) {
  extern __shared__ char smem[];
  unsigned short* sAbar = (unsigned short*)smem;           // 64 KB bf16 swizzled
  unsigned short* sG    = (unsigned short*)(smem + 65536); // 2 x [32][256] bf16 swz

  const int tid  = threadIdx.x;
  const int wv_  = tid >> 6;
  const int lane = tid & 63;
  const int l = lane & 15;     // MFMA: A row / B col / D col
  const int q = lane >> 4;     // MFMA quad
  const int mt = wv_ & 1;      // m-tile
  const int ng = wv_ >> 1;     // n-group (= head for G1 cols)

  // ---- attention geometry: thread = (pair ap, head ah, quarter au) ----
  const int ap = tid >> 4, asub = tid & 15;
  const int ah = asub >> 2, au = asub & 3;
  const int aoG0 = swz(ap, ah * 64 + au * 16);
  const int aoG1 = swz(ap, ah * 64 + au * 16 + 8);

  const int p2g = mt * 16 + l;                              // GEMM2 A-row

  // ---- prologue: Abar -> LDS (swizzled) ----
#pragma unroll
  for (int k2 = 0; k2 < 8; ++k2) {
    int id = k2 * 512 + tid, n = id >> 4, blk = id & 15;
    short8 v = *(const short8*)(AbarT + n * 128 + blk * 8);
    *(short8*)(sAbar + n * 128 + ((blk ^ (n & 15)) << 3)) = v;
  }
  // ---- Mbar -> regs (wave-sliced: 2 o-tiles x 8 kk) ----
  short8 mb0[8], mb1[8];
#pragma unroll
  for (int kk = 0; kk < 8; ++kk) {
    mb0[kk] = *(const short8*)(MbarT + (size_t)(ng * 32 + l) * 256 + kk * 32 + q * 8);
    mb1[kk] = *(const short8*)(MbarT + (size_t)(ng * 32 + 16 + l) * 256 + kk * 32 + q * 8);
  }
  const float bo0 = bo[ng * 32 + l];
  const float bo1 = bo[ng * 32 + 16 + l];
  SB();
  // ---- issue K(0) (global->reg, 16 float4) then z(0). Issued after the sAbar
  //      staging so its vmcnt waits don't drain them; both ride across BAR. ----
  float4 kt[4][4];   // kt[t][j]: t2d[t][P0+ap][au*16 + 4j .. +4)
  {
    const float* kb = t2d + ((size_t)blockIdx.x * PB + ap) * 64 + au * 16;
#pragma unroll
    for (int t = 0; t < 4; ++t)
#pragma unroll
      for (int j = 0; j < 4; ++j)
        kt[t][j] = *(const float4*)(kb + (size_t)t * (P_ * 64) + 4 * j);
  }
  SB();
  float4 zb[8];
  {
    const float* zr = z2d + ((size_t)blockIdx.x * PB + mt * 16 + l) * 128;
#pragma unroll
    for (int kk = 0; kk < 4; ++kk) {
      zb[2 * kk]     = *(const float4*)(zr + kk * 32 + q * 8);
      zb[2 * kk + 1] = *(const float4*)(zr + kk * 32 + q * 8 + 4);
    }
  }
  BAR();   // sAbar visible; K(0)/z(0) in flight

#pragma unroll 1
  for (int k = 0; k < NT_; ++k) {
    const int sl = k & 1;
    const size_t P0  = (size_t)(blockIdx.x + (size_t)k * NPB) * PB;
    const size_t P0n = P0 + (size_t)NPB * PB;

    // ======== phase X ========
    // (1) GEMM2 tile k-1: S(sG[sl^1]) @ Mbar(regs) -> out
    if (k > 0) {
      const unsigned short* sGp = sG + (sl ^ 1) * 8192;
      f32x4 a20 = f32x4{0.f, 0.f, 0.f, 0.f};
      f32x4 a21 = f32x4{0.f, 0.f, 0.f, 0.f};
#pragma unroll
      for (int kk = 0; kk < 8; ++kk) {
        short8 af2 = *(const short8*)(sGp + p2g * 256 + (((kk * 4 + q) ^ p2g) << 3));
        a20 = __builtin_amdgcn_mfma_f32_16x16x32_bf16(af2, mb0[kk], a20, 0, 0, 0);
        a21 = __builtin_amdgcn_mfma_f32_16x16x32_bf16(af2, mb1[kk], a21, 0, 0, 0);
      }
      const size_t rb = (P0 - (size_t)NPB * PB + (size_t)(mt * 16 + q * 4)) * 128;
#pragma unroll
      for (int r = 0; r < 4; ++r) {
        out[rb + r * 128 + ng * 32 + l]      = a20[r] + bo0;
        out[rb + r * 128 + ng * 32 + 16 + l] = a21[r] + bo1;
      }
    }
    SB();
    // (2) GEMM1 tile k: af=cvt(zb) — the compiler's vmcnt wait here retires
    //     z(k) (K(k) is newer: stays in flight). B from sAbar; G -> sG[sl].
    {
      f32x4 a1[4];
#pragma unroll
      for (int i = 0; i < 4; ++i) a1[i] = f32x4{0.f, 0.f, 0.f, 0.f};
#pragma unroll
      for (int kk = 0; kk < 4; ++kk) {
        S8U af;
        af.u[0] = cvtpk(zb[2 * kk].x,     zb[2 * kk].y);
        af.u[1] = cvtpk(zb[2 * kk].z,     zb[2 * kk].w);
        af.u[2] = cvtpk(zb[2 * kk + 1].x, zb[2 * kk + 1].y);
        af.u[3] = cvtpk(zb[2 * kk + 1].z, zb[2 * kk + 1].w);
#pragma unroll
        for (int i = 0; i < 4; ++i) {
          const int n = (ng * 4 + i) * 16 + l;
          short8 bf = *(const short8*)(sAbar + n * 128 + (((kk * 4 + q) ^ l) << 3));
          a1[i] = __builtin_amdgcn_mfma_f32_16x16x32_bf16(af.s8, bf, a1[i], 0, 0, 0);
        }
      }
      unsigned short* sGc = sG + sl * 8192;
#pragma unroll
      for (int i = 0; i < 4; ++i) {
        const int c = (ng * 4 + i) * 16 + l;
#pragma unroll
        for (int r = 0; r < 4; ++r)
          sGc[swz(mt * 16 + q * 4 + r, c)] = f2bf(a1[i][r]);  // m89-verified D layout
      }
    }
    SB();
    // (3) z(k+1) -> zb (in flight across Y(k) + next BAR)
    if (k + 1 < NT_) {
      const float* zr = z2d + (P0n + (size_t)(mt * 16 + l)) * 128;
#pragma unroll
      for (int kk = 0; kk < 4; ++kk) {
        zb[2 * kk]     = *(const float4*)(zr + kk * 32 + q * 8);
        zb[2 * kk + 1] = *(const float4*)(zr + kk * 32 + q * 8 + 4);
      }
    }
    SB();
    BAR();

    // ======== phase Y: attention (K in registers; S-pass reuses them) ========
    {
      unsigned short* sGc = sG + sl * 8192;
      short8 g0 = *(const short8*)(sGc + aoG0);
      short8 g1 = *(const short8*)(sGc + aoG1);
      float lg0 = 0.f, lg1 = 0.f, lg2 = 0.f, lg3 = 0.f;
#pragma unroll
      for (int j = 0; j < 4; ++j) {
        const float ga = bf2f((unsigned short)((j < 2) ? g0[4 * j]     : g1[4 * (j - 2)]));
        const float gb = bf2f((unsigned short)((j < 2) ? g0[4 * j + 1] : g1[4 * (j - 2) + 1]));
        const float gc = bf2f((unsigned short)((j < 2) ? g0[4 * j + 2] : g1[4 * (j - 2) + 2]));
        const float gd = bf2f((unsigned short)((j < 2) ? g0[4 * j + 3] : g1[4 * (j - 2) + 3]));
        lg0 += ga * kt[0][j].x + gb * kt[0][j].y + gc * kt[0][j].z + gd * kt[0][j].w;
        lg1 += ga * kt[1][j].x + gb * kt[1][j].y + gc * kt[1][j].z + gd * kt[1][j].w;
        lg2 += ga * kt[2][j].x + gb * kt[2][j].y + gc * kt[2][j].z + gd * kt[2][j].w;
        lg3 += ga * kt[3][j].x + gb * kt[3][j].y + gc * kt[3][j].z + gd * kt[3][j].w;
      }
      lg0 += __shfl_xor(lg0, 1); lg0 += __shfl_xor(lg0, 2);
      lg1 += __shfl_xor(lg1, 1); lg1 += __shfl_xor(lg1, 2);
      lg2 += __shfl_xor(lg2, 1); lg2 += __shfl_xor(lg2, 2);
      lg3 += __shfl_xor(lg3, 1); lg3 += __shfl_xor(lg3, 2);
      const float mx = fmaxf(fmaxf(lg0, lg1), fmaxf(lg2, lg3));
      float e0 = __expf(lg0 - mx), e1 = __expf(lg1 - mx);
      float e2 = __expf(lg2 - mx), e3 = __expf(lg3 - mx);
      const float inv = 1.f / (e0 + e1 + e2 + e3);
      e0 *= inv; e1 *= inv; e2 *= inv; e3 *= inv;
      // S[ap][ah*64+au*16+4j..+4) = sum_t e_t * K_t — straight from registers
#pragma unroll
      for (int j = 0; j < 4; ++j) {
        float s0 = e0 * kt[0][j].x + e1 * kt[1][j].x + e2 * kt[2][j].x + e3 * kt[3][j].x;
        float s1 = e0 * kt[0][j].y + e1 * kt[1][j].y + e2 * kt[2][j].y + e3 * kt[3][j].y;
        float s2 = e0 * kt[0][j].z + e1 * kt[1][j].z + e2 * kt[2][j].z + e3 * kt[3][j].z;
        float s3 = e0 * kt[0][j].w + e1 * kt[1][j].w + e2 * kt[2][j].w + e3 * kt[3][j].w;
        uint2 w2; w2.x = cvtpk(s0, s1); w2.y = cvtpk(s2, s3);
        *(uint2*)(sGc + swz(ap, ah * 64 + au * 16 + 4 * j)) = w2;   // 8B, aligned
      }
    }
    SB();
    // (4) issue K(k+1) (last K(k) use was the S-pass above; regs recycle).
    //     In flight across BAR + G2 + G1 of iter k+1 — covers HBM latency.
    if (k + 1 < NT_) {
      const float* kb = t2d + (P0n + ap) * 64 + au * 16;
#pragma unroll
      for (int t = 0; t < 4; ++t)
#pragma unroll
        for (int j = 0; j < 4; ++j)
          kt[t][j] = *(const float4*)(kb + (size_t)t * (P_ * 64) + 4 * j);
    }
    SB();
    BAR();
  }

  // ---- tail: GEMM2 for the last tile (sl of NT_-1 = 1) ----
  {
    const unsigned short* sGp = sG + 8192;
    f32x4 a20 = f32x4{0.f, 0.f, 0.f, 0.f};
    f32x4 a21 = f32x4{0.f, 0.f, 0.f, 0.f};
#pragma unroll
    for (int kk = 0; kk < 8; ++kk) {
      short8 af2 = *(const short8*)(sGp + p2g * 256 + (((kk * 4 + q) ^ p2g) << 3));
      a20 = __builtin_amdgcn_mfma_f32_16x16x32_bf16(af2, mb0[kk], a20, 0, 0, 0);
      a21 = __builtin_amdgcn_mfma_f32_16x16x32_bf16(af2, mb1[kk], a21, 0, 0, 0);
    }
    const size_t rb = ((size_t)(blockIdx.x + (size_t)(NT_ - 1) * NPB) * PB
                       + (size_t)(mt * 16 + q * 4)) * 128;
#pragma unroll
    for (int r = 0; r < 4; ++r) {
      out[rb + r * 128 + ng * 32 + l]      = a20[r] + bo0;
      out[rb + r * 128 + ng * 32 + 16 + l] = a21[r] + bo1;
    }
  }
}

extern "C" void kernel_launch(void* const* d_in, const int* in_sizes, int n_in,
                              void* d_out, int out_size, void* d_ws, size_t ws_size,
                              hipStream_t stream) {
  const float* z2d = (const float*)d_in[0];
  const float* t2d = (const float*)d_in[1];
  const float* Wq  = (const float*)d_in[2];
  const float* Wk  = (const float*)d_in[3];
  const float* Wv  = (const float*)d_in[4];
  const float* Wo  = (const float*)d_in[5];
  const float* bo  = (const float*)d_in[6];

  unsigned short* AbarT = (unsigned short*)d_ws;           // 256*128 bf16 = 64 KB
  unsigned short* MbarT = AbarT + 256 * 128;               // 128*256 bf16 = 64 KB
  float* out = (float*)d_out;

  static bool attr_set = false;
  if (!attr_set) {
    (void)hipFuncSetAttribute((const void*)attn_kernel,
                              hipFuncAttributeMaxDynamicSharedMemorySize, 98304);
    attr_set = true;
  }

  hipLaunchKernelGGL(prep_kernel, dim3(256), dim3(256), 0, stream,
                     Wq, Wk, Wv, Wo, AbarT, MbarT);
  hipLaunchKernelGGL(attn_kernel, dim3(NPB), dim3(512), 98304, stream,
                     z2d, t2d, AbarT, MbarT, bo, out);
}